// Round 4
// baseline (2980.772 us; speedup 1.0000x reference)
//
#include <hip/hip_runtime.h>
#include <cstdint>

typedef _Float16 f16;
typedef _Float16 f16x2 __attribute__((ext_vector_type(2)));

#define T_STEPS 512
#define B_SZ 512
#define LOG2PI 1.8378770664093453f

__device__ __forceinline__ uint32_t packh2(float a, float b) {
  f16x2 v; v[0] = (f16)a; v[1] = (f16)b;
  return __builtin_bit_cast(uint32_t, v);
}

__device__ __forceinline__ float fdot2(uint32_t a, uint32_t b, float c) {
#if defined(__AMDGCN__) && __has_builtin(__builtin_amdgcn_fdot2)
  return __builtin_amdgcn_fdot2(__builtin_bit_cast(f16x2, a),
                                __builtin_bit_cast(f16x2, b), c, false);
#else
  f16x2 x = __builtin_bit_cast(f16x2, a), y = __builtin_bit_cast(f16x2, b);
  return c + (float)x[0] * (float)y[0] + (float)x[1] * (float)y[1];
#endif
}

#define DOT4(acc, w0, w1, w2, w3, v)                                     \
  do {                                                                   \
    acc = fdot2((w0), (v).x, acc); acc = fdot2((w1), (v).y, acc);        \
    acc = fdot2((w2), (v).z, acc); acc = fdot2((w3), (v).w, acc);        \
  } while (0)

__device__ __forceinline__ float sigmoidf_(float x) {
  return 1.0f / (1.0f + __expf(-x));
}
__device__ __forceinline__ float tanhf_(float x) {
  float ax = fabsf(x);
  float t = __expf(-2.0f * ax);
  float r = (1.0f - t) / (1.0f + t);
  return copysignf(r, x);
}
__device__ __forceinline__ float softplusf_(float x) {
  return fmaxf(x, 0.0f) + __logf(1.0f + __expf(-fabsf(x)));
}

// ---------------------------------------------------------------------------
// Kernel 1: embedding / state_t construction.  state_t: (T,B,32) f16.
// ---------------------------------------------------------------------------
__global__ __launch_bounds__(256) void k_embed(
    const float* __restrict__ xs, const float* __restrict__ shot_emb,
    const float* __restrict__ player_emb, f16* __restrict__ state_t,
    float* __restrict__ accums) {
  if (blockIdx.x == 0 && threadIdx.x < 16) accums[threadIdx.x] = 0.0f;
  size_t idx = (size_t)blockIdx.x * 256 + threadIdx.x;
  const float* xp = xs + idx * 23;
  f16* op = state_t + idx * 32;
  int sid = (int)xp[12];
  int pid = (int)xp[17];
#pragma unroll
  for (int i = 0; i < 12; ++i) op[i] = (f16)xp[i];
  const float* se = shot_emb + sid * 8;
#pragma unroll
  for (int i = 0; i < 8; ++i) op[12 + i] = (f16)se[i];
#pragma unroll
  for (int i = 0; i < 4; ++i) op[20 + i] = (f16)xp[13 + i];
  const float* pe = player_emb + pid * 8;
#pragma unroll
  for (int i = 0; i < 8; ++i) op[24 + i] = (f16)pe[i];
}

// ---------------------------------------------------------------------------
// Kernel 2: backward GRU scan + encoder + qz0 head.
// 512 blocks x 256 threads, 1 batch/block, 2 blocks/CU.
// x-row read as wave-uniform load (SGPR operand to fdot2) - no LDS for x.
// tid 0-127  : rows R_d, Z_d (2 rows/thread, combined i+h bias)
// tid 128-191: rows N_{2u}, N_{2u+1} (separate i/h sums)
// tid 192-255: enc row c -> LDS ctx ring (flushed every 64 steps)
// 2 barriers/step.
// ---------------------------------------------------------------------------
__global__ __launch_bounds__(256, 2) void k_gru(
    const f16* __restrict__ state_t, const float* __restrict__ wih,
    const float* __restrict__ whh, const float* __restrict__ bih,
    const float* __restrict__ bhh, const float* __restrict__ enc_w,
    const float* __restrict__ enc_b, const float* __restrict__ qz0_w,
    const float* __restrict__ qz0_b, const float* __restrict__ z0_noise,
    const float* __restrict__ pz0_mean, const float* __restrict__ pz0_logstd,
    f16* __restrict__ ctx, float* __restrict__ z0_out,
    float* __restrict__ accums) {
  __shared__ __align__(16) uint32_t s_h[64];        // h, f16x2
  __shared__ __align__(16) float s_grz[128][2];     // (aR,aZ) per d
  __shared__ __align__(16) float s_gn[128][2];      // (iN,hN) per d
  __shared__ __align__(16) f16 s_cbuf[64][64];      // ctx ring (8 KB)
  __shared__ float s_ctx0[64];
  __shared__ float s_q[32];

  const int tid = threadIdx.x;
  const int bg = blockIdx.x;
  const uint32_t* stu = (const uint32_t*)state_t;

  uint32_t wh0[64], wh1[64], wx0[16], wx1[16];
  float b0 = 0.f, b1 = 0.f, b0h = 0.f, b1h = 0.f, encbr = 0.f;

  if (tid < 128) {
    const float* r0 = whh + (size_t)tid * 128;
    const float* r1 = whh + (size_t)(128 + tid) * 128;
#pragma unroll
    for (int i = 0; i < 64; ++i) {
      wh0[i] = packh2(r0[2 * i], r0[2 * i + 1]);
      wh1[i] = packh2(r1[2 * i], r1[2 * i + 1]);
    }
    const float* x0 = wih + (size_t)tid * 32;
    const float* x1 = wih + (size_t)(128 + tid) * 32;
#pragma unroll
    for (int i = 0; i < 16; ++i) {
      wx0[i] = packh2(x0[2 * i], x0[2 * i + 1]);
      wx1[i] = packh2(x1[2 * i], x1[2 * i + 1]);
    }
    b0 = bih[tid] + bhh[tid];
    b1 = bih[128 + tid] + bhh[128 + tid];
  } else if (tid < 192) {
    int u = tid - 128;
    const float* r0 = whh + (size_t)(256 + 2 * u) * 128;
    const float* r1 = whh + (size_t)(256 + 2 * u + 1) * 128;
#pragma unroll
    for (int i = 0; i < 64; ++i) {
      wh0[i] = packh2(r0[2 * i], r0[2 * i + 1]);
      wh1[i] = packh2(r1[2 * i], r1[2 * i + 1]);
    }
    const float* x0 = wih + (size_t)(256 + 2 * u) * 32;
    const float* x1 = wih + (size_t)(256 + 2 * u + 1) * 32;
#pragma unroll
    for (int i = 0; i < 16; ++i) {
      wx0[i] = packh2(x0[2 * i], x0[2 * i + 1]);
      wx1[i] = packh2(x1[2 * i], x1[2 * i + 1]);
    }
    b0 = bih[256 + 2 * u];
    b0h = bhh[256 + 2 * u];
    b1 = bih[256 + 2 * u + 1];
    b1h = bhh[256 + 2 * u + 1];
  } else {
    int c = tid - 192;
    const float* er = enc_w + (size_t)c * 128;
#pragma unroll
    for (int i = 0; i < 64; ++i) wh0[i] = packh2(er[2 * i], er[2 * i + 1]);
    encbr = enc_b[c];
  }

  if (tid < 64) s_h[tid] = 0u;
  float h_old = 0.0f;
  __syncthreads();

  for (int t = T_STEPS - 1; t >= 0; --t) {
    // wave-uniform x row (64B) -> scalar/broadcast load
    const uint4* xr = (const uint4*)(stu + ((size_t)t * B_SZ + bg) * 16);
    uint4 xv0 = xr[0], xv1 = xr[1], xv2 = xr[2], xv3 = xr[3];
    // ---- Phase A
    if (tid < 128) {
      float aR = b0, aRb = 0.f, aZ = b1, aZb = 0.f;
      DOT4(aR, wx0[0], wx0[1], wx0[2], wx0[3], xv0);
      DOT4(aRb, wx0[4], wx0[5], wx0[6], wx0[7], xv1);
      DOT4(aR, wx0[8], wx0[9], wx0[10], wx0[11], xv2);
      DOT4(aRb, wx0[12], wx0[13], wx0[14], wx0[15], xv3);
      DOT4(aZ, wx1[0], wx1[1], wx1[2], wx1[3], xv0);
      DOT4(aZb, wx1[4], wx1[5], wx1[6], wx1[7], xv1);
      DOT4(aZ, wx1[8], wx1[9], wx1[10], wx1[11], xv2);
      DOT4(aZb, wx1[12], wx1[13], wx1[14], wx1[15], xv3);
      const uint4* hq = (const uint4*)s_h;
#pragma unroll
      for (int j = 0; j < 16; ++j) {
        uint4 v = hq[j];
        if (j & 1) {
          DOT4(aRb, wh0[4 * j], wh0[4 * j + 1], wh0[4 * j + 2], wh0[4 * j + 3], v);
          DOT4(aZb, wh1[4 * j], wh1[4 * j + 1], wh1[4 * j + 2], wh1[4 * j + 3], v);
        } else {
          DOT4(aR, wh0[4 * j], wh0[4 * j + 1], wh0[4 * j + 2], wh0[4 * j + 3], v);
          DOT4(aZ, wh1[4 * j], wh1[4 * j + 1], wh1[4 * j + 2], wh1[4 * j + 3], v);
        }
      }
      *(float2*)&s_grz[tid][0] = make_float2(aR + aRb, aZ + aZb);
    } else if (tid < 192) {
      int u = tid - 128;
      float aI0 = b0, aI0b = 0.f, aI1 = b1, aI1b = 0.f;
      DOT4(aI0, wx0[0], wx0[1], wx0[2], wx0[3], xv0);
      DOT4(aI0b, wx0[4], wx0[5], wx0[6], wx0[7], xv1);
      DOT4(aI0, wx0[8], wx0[9], wx0[10], wx0[11], xv2);
      DOT4(aI0b, wx0[12], wx0[13], wx0[14], wx0[15], xv3);
      DOT4(aI1, wx1[0], wx1[1], wx1[2], wx1[3], xv0);
      DOT4(aI1b, wx1[4], wx1[5], wx1[6], wx1[7], xv1);
      DOT4(aI1, wx1[8], wx1[9], wx1[10], wx1[11], xv2);
      DOT4(aI1b, wx1[12], wx1[13], wx1[14], wx1[15], xv3);
      float aH0 = b0h, aH0b = 0.f, aH1 = b1h, aH1b = 0.f;
      const uint4* hq = (const uint4*)s_h;
#pragma unroll
      for (int j = 0; j < 16; ++j) {
        uint4 v = hq[j];
        if (j & 1) {
          DOT4(aH0b, wh0[4 * j], wh0[4 * j + 1], wh0[4 * j + 2], wh0[4 * j + 3], v);
          DOT4(aH1b, wh1[4 * j], wh1[4 * j + 1], wh1[4 * j + 2], wh1[4 * j + 3], v);
        } else {
          DOT4(aH0, wh0[4 * j], wh0[4 * j + 1], wh0[4 * j + 2], wh0[4 * j + 3], v);
          DOT4(aH1, wh1[4 * j], wh1[4 * j + 1], wh1[4 * j + 2], wh1[4 * j + 3], v);
        }
      }
      *(float4*)&s_gn[2 * u][0] =
          make_float4(aI0 + aI0b, aH0 + aH0b, aI1 + aI1b, aH1 + aH1b);
    } else if (t < T_STEPS - 1) {
      int c = tid - 192;
      float e0 = encbr, e1 = 0.f;
      const uint4* hq = (const uint4*)s_h;
#pragma unroll
      for (int j = 0; j < 16; ++j) {
        uint4 v = hq[j];
        if (j & 1) {
          DOT4(e1, wh0[4 * j], wh0[4 * j + 1], wh0[4 * j + 2], wh0[4 * j + 3], v);
        } else {
          DOT4(e0, wh0[4 * j], wh0[4 * j + 1], wh0[4 * j + 2], wh0[4 * j + 3], v);
        }
      }
      s_cbuf[(t + 1) & 63][c] = (f16)(e0 + e1);
    }
    __syncthreads();
    // ---- Phase B: h update (tid<128); ctx flush (w3, every 64 steps)
    if (tid < 128) {
      float2 rz = *(const float2*)&s_grz[tid][0];
      float2 nn = *(const float2*)&s_gn[tid][0];
      float r = sigmoidf_(rz.x);
      float zg = sigmoidf_(rz.y);
      float n = tanhf_(nn.x + r * nn.y);
      float hnew = (1.0f - zg) * n + zg * h_old;
      h_old = hnew;
      ((f16*)s_h)[tid] = (f16)hnew;
    } else if (tid >= 192 && (t & 63) == 63) {
      int lane = tid & 63;
      int seg = lane & 7;
#pragma unroll
      for (int it = 0; it < 8; ++it) {
        int row = (t + 1) + it * 8 + (lane >> 3);
        uint4 v = *(const uint4*)((const uint32_t*)&s_cbuf[row & 63][0] + seg * 4);
        *(uint4*)((uint32_t*)ctx + ((size_t)row * B_SZ + bg) * 32 + seg * 4) = v;
      }
    }
    __syncthreads();
  }

  // ---- Tail: enc(h(0)) -> ctx[0]; flush chunk 0; qz0; z0 + KL
  if (tid >= 192) {
    int c = tid - 192;
    float e0 = encbr, e1 = 0.f;
    const uint4* hq = (const uint4*)s_h;
#pragma unroll
    for (int j = 0; j < 16; ++j) {
      uint4 v = hq[j];
      if (j & 1) {
        DOT4(e1, wh0[4 * j], wh0[4 * j + 1], wh0[4 * j + 2], wh0[4 * j + 3], v);
      } else {
        DOT4(e0, wh0[4 * j], wh0[4 * j + 1], wh0[4 * j + 2], wh0[4 * j + 3], v);
      }
    }
    float val = e0 + e1;
    s_ctx0[c] = val;
    s_cbuf[0][c] = (f16)val;
  }
  __syncthreads();
  if (tid >= 192) {
    int lane = tid & 63;
    int seg = lane & 7;
#pragma unroll
    for (int it = 0; it < 8; ++it) {
      int row = it * 8 + (lane >> 3);
      uint4 v = *(const uint4*)((const uint32_t*)&s_cbuf[row][0] + seg * 4);
      *(uint4*)((uint32_t*)ctx + ((size_t)row * B_SZ + bg) * 32 + seg * 4) = v;
    }
  } else if (tid < 32) {
    float acc = qz0_b[tid];
#pragma unroll 8
    for (int k = 0; k < 64; ++k) acc += qz0_w[tid * 64 + k] * s_ctx0[k];
    s_q[tid] = acc;
  }
  __syncthreads();
  if (tid < 16) {
    float qm = s_q[tid], qls = s_q[16 + tid];
    float z0v = qm + __expf(qls) * z0_noise[bg * 16 + tid];
    z0_out[bg * 16 + tid] = z0v;
    float pm = pz0_mean[tid], pls = pz0_logstd[tid];
    float var_q = __expf(2.0f * qls);
    float var_p = __expf(2.0f * pls);
    float dm = qm - pm;
    float kl = pls - qls + (var_q + dm * dm) / (2.0f * var_p) - 0.5f;
    atomicAdd(&accums[5], kl);
  }
}

// ---------------------------------------------------------------------------
// Kernel 3: SDE scan. 512 blocks x 256 threads, 2 blocks/CU, 3 barriers/step.
// ctx row via wave-uniform load (SGPR fdot2 operand). zs buffered in LDS.
// w0 (0-63):   A: f1 2 rows; C: f3/h3 slices + shuffle-reduce; D: z update.
// w1 (64-127): A: g units 0-63;  B: fw2 2 rows.
// w2 (128-191):A: h1 2 rows;     B: hw2 2 rows.
// w3 (192-255):A: g units 64-127.
// ---------------------------------------------------------------------------
__global__ __launch_bounds__(256, 2) void k_sde(
    const f16* __restrict__ ctx, const float* __restrict__ z0_in,
    const float* __restrict__ ts, const float* __restrict__ bm_noise,
    const float* __restrict__ fw1, const float* __restrict__ fb1,
    const float* __restrict__ fw2, const float* __restrict__ fb2,
    const float* __restrict__ fw3, const float* __restrict__ fb3,
    const float* __restrict__ hw1, const float* __restrict__ hb1,
    const float* __restrict__ hw2, const float* __restrict__ hb2,
    const float* __restrict__ hw3, const float* __restrict__ hb3,
    const float* __restrict__ gw1, const float* __restrict__ gb1,
    const float* __restrict__ gw2, const float* __restrict__ gb2,
    f16* __restrict__ zs, float* __restrict__ accums) {
  __shared__ __align__(16) uint32_t s_x2z[8];      // z as f16x2
  __shared__ float s_zf[16];                       // z f32 (for g)
  __shared__ __align__(16) uint32_t s_h1f[64];
  __shared__ __align__(16) uint32_t s_h1h[64];
  __shared__ __align__(16) uint32_t s_h2[2][64];
  __shared__ float s_gpw[2][16];                   // g partials per half
  __shared__ __align__(16) float s_v3[32];         // f3|h3 sums
  __shared__ float s_dts[T_STEPS];
  __shared__ __align__(16) f16 s_zbuf[T_STEPS * 16];  // 16 KB

  const int tid = threadIdx.x;
  const int bg = blockIdx.x;

  uint32_t wa[80];   // w0: f1 2 rows | w1/w2: layer2 2 rows (64+..)
  uint32_t wb[32];   // w0: wp3 | w2: h1 2 rows (16 used)
  float gw1v[16], gb1v[16], gw2v[16];
  float ba = 0.f, bb = 0.f, fb3r = 0.f, hb3r = 0.f, gb2r = 0.f;

  if (tid < 64) {
    const float* r0 = fw1 + (size_t)(2 * tid) * 80;
    const float* r1 = fw1 + (size_t)(2 * tid + 1) * 80;
#pragma unroll
    for (int i = 0; i < 40; ++i) {
      wa[i] = packh2(r0[2 * i], r0[2 * i + 1]);
      wa[40 + i] = packh2(r1[2 * i], r1[2 * i + 1]);
    }
    ba = fb1[2 * tid];
    bb = fb1[2 * tid + 1];
    int k8 = tid >> 3, mlp = (tid >> 2) & 1, o4 = tid & 3;
    const float* w3src = mlp ? hw3 : fw3;
#pragma unroll
    for (int oo = 0; oo < 4; ++oo)
#pragma unroll
      for (int j = 0; j < 8; ++j)
        wb[oo * 8 + j] = packh2(w3src[(o4 * 4 + oo) * 128 + k8 * 16 + 2 * j],
                                w3src[(o4 * 4 + oo) * 128 + k8 * 16 + 2 * j + 1]);
    if (tid < 16) {
      fb3r = fb3[tid];
      hb3r = hb3[tid];
      gb2r = gb2[tid];
    }
  } else if (tid < 128) {
    int u = tid - 64;
    const float* r0 = fw2 + (size_t)(2 * u) * 128;
    const float* r1 = fw2 + (size_t)(2 * u + 1) * 128;
#pragma unroll
    for (int i = 0; i < 64; ++i) {
      wa[i] = packh2(r0[2 * i], r0[2 * i + 1]);
      wb[i & 15] = wb[i & 15];  // no-op
    }
    // second row into a separate array region: reuse gw arrays? keep wa only 64;
    // store row1 into registers via wb (32) + extra: use dedicated array below.
    ba = fb2[2 * u];
    bb = fb2[2 * u + 1];
    int l = u & 15, c4 = u >> 4;
#pragma unroll
    for (int j = 0; j < 16; ++j) {
      int h = c4 * 16 + j;
      gw1v[j] = gw1[l * 128 + h];
      gb1v[j] = gb1[l * 128 + h];
      gw2v[j] = gw2[l * 128 + h];
    }
  } else if (tid < 192) {
    int u = tid - 128;
    const float* r0 = hw2 + (size_t)(2 * u) * 128;
#pragma unroll
    for (int i = 0; i < 64; ++i) wa[i] = packh2(r0[2 * i], r0[2 * i + 1]);
    const float* z0r = hw1 + (size_t)(2 * u) * 16;
    const float* z1r = hw1 + (size_t)(2 * u + 1) * 16;
#pragma unroll
    for (int i = 0; i < 8; ++i) {
      wb[i] = packh2(z0r[2 * i], z0r[2 * i + 1]);
      wb[8 + i] = packh2(z1r[2 * i], z1r[2 * i + 1]);
    }
    ba = hb2[2 * u];
    bb = hb2[2 * u + 1];
  } else {
    int i2 = tid - 192;
    int l = i2 & 15, c4 = i2 >> 4;
#pragma unroll
    for (int j = 0; j < 16; ++j) {
      int h = 64 + c4 * 16 + j;
      gw1v[j] = gw1[l * 128 + h];
      gb1v[j] = gb1[l * 128 + h];
      gw2v[j] = gw2[l * 128 + h];
    }
  }
  // second layer-2 row for w1/w2 (kept in its own array so paths stay <256 VGPR)
  uint32_t wc[64];
  if (tid >= 64 && tid < 128) {
    int u = tid - 64;
    const float* r1 = fw2 + (size_t)(2 * u + 1) * 128;
#pragma unroll
    for (int i = 0; i < 64; ++i) wc[i] = packh2(r1[2 * i], r1[2 * i + 1]);
  } else if (tid >= 128 && tid < 192) {
    int u = tid - 128;
    const float* r1 = hw2 + (size_t)(2 * u + 1) * 128;
#pragma unroll
    for (int i = 0; i < 64; ++i) wc[i] = packh2(r1[2 * i], r1[2 * i + 1]);
  }
  // layer-1 biases for w2's two h1 rows
  float hb1a = 0.f, hb1b = 0.f;
  if (tid >= 128 && tid < 192) {
    int u = tid - 128;
    hb1a = hb1[2 * u];
    hb1b = hb1[2 * u + 1];
  }

  for (int i = tid; i < T_STEPS - 1; i += 256) s_dts[i] = ts[i + 1] - ts[i];
  float zf_r = 0.f;
  if (tid < 16) {
    zf_r = z0_in[bg * 16 + tid];
    s_zf[tid] = zf_r;
    s_zbuf[tid] = (f16)zf_r;
  }
  if (tid < 8) {
    float za = z0_in[bg * 16 + 2 * tid], zb = z0_in[bg * 16 + 2 * tid + 1];
    s_x2z[tid] = packh2(za, zb);
  }
  float path_acc = 0.0f;
  __syncthreads();

  for (int t = 0; t < T_STEPS - 1; ++t) {
    float bm_cur = 0.f;
    if (tid < 16) bm_cur = bm_noise[((size_t)t * B_SZ + bg) * 16 + tid];
    // ---- Phase A
    if (tid < 64) {
      // wave-uniform ctx row t+1 (128B)
      const uint4* cr =
          (const uint4*)((const uint32_t*)ctx + ((size_t)(t + 1) * B_SZ + bg) * 32);
      uint4 c0 = cr[0], c1 = cr[1], c2 = cr[2], c3 = cr[3];
      uint4 c4v = cr[4], c5 = cr[5], c6 = cr[6], c7 = cr[7];
      const uint4* zq = (const uint4*)s_x2z;
      uint4 zv0 = zq[0], zv1 = zq[1];
      float a0 = ba, a0b = 0.f, a1 = bb, a1b = 0.f;
      DOT4(a0, wa[0], wa[1], wa[2], wa[3], zv0);
      DOT4(a0b, wa[4], wa[5], wa[6], wa[7], zv1);
      DOT4(a1, wa[40], wa[41], wa[42], wa[43], zv0);
      DOT4(a1b, wa[44], wa[45], wa[46], wa[47], zv1);
      DOT4(a0, wa[8], wa[9], wa[10], wa[11], c0);
      DOT4(a0b, wa[12], wa[13], wa[14], wa[15], c1);
      DOT4(a0, wa[16], wa[17], wa[18], wa[19], c2);
      DOT4(a0b, wa[20], wa[21], wa[22], wa[23], c3);
      DOT4(a0, wa[24], wa[25], wa[26], wa[27], c4v);
      DOT4(a0b, wa[28], wa[29], wa[30], wa[31], c5);
      DOT4(a0, wa[32], wa[33], wa[34], wa[35], c6);
      DOT4(a0b, wa[36], wa[37], wa[38], wa[39], c7);
      DOT4(a1, wa[48], wa[49], wa[50], wa[51], c0);
      DOT4(a1b, wa[52], wa[53], wa[54], wa[55], c1);
      DOT4(a1, wa[56], wa[57], wa[58], wa[59], c2);
      DOT4(a1b, wa[60], wa[61], wa[62], wa[63], c3);
      DOT4(a1, wa[64], wa[65], wa[66], wa[67], c4v);
      DOT4(a1b, wa[68], wa[69], wa[70], wa[71], c5);
      DOT4(a1, wa[72], wa[73], wa[74], wa[75], c6);
      DOT4(a1b, wa[76], wa[77], wa[78], wa[79], c7);
      s_h1f[tid] = packh2(softplusf_(a0 + a0b), softplusf_(a1 + a1b));
    } else if (tid < 128 || tid >= 192) {
      int i2 = (tid < 128) ? (tid - 64) : (tid - 192);
      int half = (tid < 128) ? 0 : 1;
      int l = i2 & 15;
      float y = s_zf[l];
      float acc = 0.f;
#pragma unroll
      for (int j = 0; j < 16; ++j) {
        float pre = fmaf(y, gw1v[j], gb1v[j]);
        acc = fmaf(softplusf_(pre), gw2v[j], acc);
      }
      acc += __shfl_xor(acc, 16);
      acc += __shfl_xor(acc, 32);
      if ((i2 & 63) < 16) s_gpw[half][l] = acc;
      if (half) goto a_done;
      // fallthrough nothing
a_done:;
    }
    if (tid >= 128 && tid < 192) {
      int u = tid - 128;
      const uint4* zq = (const uint4*)s_x2z;
      uint4 zv0 = zq[0], zv1 = zq[1];
      float a0 = hb1a, a0b = 0.f, a1 = hb1b, a1b = 0.f;
      DOT4(a0, wb[0], wb[1], wb[2], wb[3], zv0);
      DOT4(a0b, wb[4], wb[5], wb[6], wb[7], zv1);
      DOT4(a1, wb[8], wb[9], wb[10], wb[11], zv0);
      DOT4(a1b, wb[12], wb[13], wb[14], wb[15], zv1);
      s_h1h[u] = packh2(softplusf_(a0 + a0b), softplusf_(a1 + a1b));
    }
    __syncthreads();
    // ---- Phase B: layer-2, 2 rows/thread
    if (tid >= 64 && tid < 192) {
      int isH = tid >= 128;
      int u = isH ? (tid - 128) : (tid - 64);
      const uint4* hq = (const uint4*)(isH ? s_h1h : s_h1f);
      float a0 = ba, a0b = 0.f, a1 = bb, a1b = 0.f;
#pragma unroll
      for (int j = 0; j < 16; ++j) {
        uint4 v = hq[j];
        if (j & 1) {
          DOT4(a0b, wa[4 * j], wa[4 * j + 1], wa[4 * j + 2], wa[4 * j + 3], v);
          DOT4(a1b, wc[4 * j], wc[4 * j + 1], wc[4 * j + 2], wc[4 * j + 3], v);
        } else {
          DOT4(a0, wa[4 * j], wa[4 * j + 1], wa[4 * j + 2], wa[4 * j + 3], v);
          DOT4(a1, wc[4 * j], wc[4 * j + 1], wc[4 * j + 2], wc[4 * j + 3], v);
        }
      }
      s_h2[isH][u] = packh2(softplusf_(a0 + a0b), softplusf_(a1 + a1b));
    }
    __syncthreads();
    // ---- Phase C+D (w0 only)
    if (tid < 64) {
      int k8 = tid >> 3, mlp = (tid >> 2) & 1, o4 = tid & 3;
      const uint4* hq = (const uint4*)&s_h2[mlp][k8 * 8];
      uint4 hv0 = hq[0], hv1 = hq[1];
      float a0 = 0.f, a1 = 0.f, a2 = 0.f, a3 = 0.f;
      DOT4(a0, wb[0], wb[1], wb[2], wb[3], hv0);
      DOT4(a0, wb[4], wb[5], wb[6], wb[7], hv1);
      DOT4(a1, wb[8], wb[9], wb[10], wb[11], hv0);
      DOT4(a1, wb[12], wb[13], wb[14], wb[15], hv1);
      DOT4(a2, wb[16], wb[17], wb[18], wb[19], hv0);
      DOT4(a2, wb[20], wb[21], wb[22], wb[23], hv1);
      DOT4(a3, wb[24], wb[25], wb[26], wb[27], hv0);
      DOT4(a3, wb[28], wb[29], wb[30], wb[31], hv1);
      a0 += __shfl_xor(a0, 8); a0 += __shfl_xor(a0, 16); a0 += __shfl_xor(a0, 32);
      a1 += __shfl_xor(a1, 8); a1 += __shfl_xor(a1, 16); a1 += __shfl_xor(a1, 32);
      a2 += __shfl_xor(a2, 8); a2 += __shfl_xor(a2, 16); a2 += __shfl_xor(a2, 32);
      a3 += __shfl_xor(a3, 8); a3 += __shfl_xor(a3, 16); a3 += __shfl_xor(a3, 32);
      if (tid < 8)
        *(float4*)&s_v3[mlp * 16 + o4 * 4] = make_float4(a0, a1, a2, a3);
      // ---- D
      int l = tid & 15;
      float fv = s_v3[l] + fb3r;
      float hv = s_v3[16 + l] + hb3r;
      float gv = sigmoidf_(gb2r + s_gpw[0][l] + s_gpw[1][l]);
      float dt = s_dts[t];
      float uu = (fv - hv) / gv;
      float lsum = uu * uu;
      lsum += __shfl_xor(lsum, 1);
      lsum += __shfl_xor(lsum, 2);
      lsum += __shfl_xor(lsum, 4);
      lsum += __shfl_xor(lsum, 8);
      if (tid == 0) path_acc += 0.5f * lsum * dt;
      float zn = zf_r + fv * dt + gv * (sqrtf(dt) * bm_cur);
      float zo = __shfl_xor(zn, 1);
      if (tid < 16) {
        zf_r = zn;
        s_zf[tid] = zn;
        s_zbuf[(t + 1) * 16 + tid] = (f16)zn;
        if (!(tid & 1)) s_x2z[tid >> 1] = packh2(zn, zo);
      }
    }
    __syncthreads();
  }
  if (tid == 0) atomicAdd(&accums[6], path_acc);
  // flush zs buffer (512 rows x 32B)
#pragma unroll
  for (int it = 0; it < 4; ++it) {
    int idx = it * 256 + tid;
    int row = idx >> 1, half = idx & 1;
    uint4 v = *(const uint4*)((const uint32_t*)s_zbuf + row * 8 + half * 4);
    *(uint4*)((uint32_t*)zs + ((size_t)row * B_SZ + bg) * 8 + half * 4) = v;
  }
}

// ---------------------------------------------------------------------------
// Kernel 4: decoder + losses.  2 tokens per thread, uint4 LDS layouts.
// ---------------------------------------------------------------------------
__global__ __launch_bounds__(256) void k_dec(
    const f16* __restrict__ zs, const f16* __restrict__ state_t,
    const float* __restrict__ xs, const float* __restrict__ proj_w,
    const float* __restrict__ proj_b, const float* __restrict__ act_w,
    const float* __restrict__ act_b, const float* __restrict__ land_w,
    const float* __restrict__ shot_w, const float* __restrict__ move_w,
    float* __restrict__ accums) {
  __shared__ __align__(16) uint32_t s_proj[32 * 8];
  __shared__ __align__(16) uint32_t s_act[128 * 8];
  __shared__ __align__(16) uint32_t s_head[128 * 8];
  __shared__ float s_pb[32], s_ab[128];
  __shared__ float s_red[4 * 5];

  const int tid = threadIdx.x;
  if (tid < 256) {
    int i = tid >> 3, kp = tid & 7;
    s_proj[tid] = packh2(proj_w[i * 16 + 2 * kp], proj_w[i * 16 + 2 * kp + 1]);
  }
  for (int id = tid; id < 1024; id += 256) {
    int j = id >> 3, kp = id & 7;
    s_act[id] = packh2(act_w[j * 16 + 2 * kp], act_w[j * 16 + 2 * kp + 1]);
  }
  for (int id = tid; id < 1024; id += 256) {
    int j = id >> 3, p = id & 7;
    int h0 = 2 * p, h1 = 2 * p + 1;
    float w0 = (h0 < 2) ? land_w[h0 * 128 + j]
                        : (h0 < 14 ? shot_w[(h0 - 2) * 128 + j]
                                   : move_w[(h0 - 14) * 128 + j]);
    float w1 = (h1 < 2) ? land_w[h1 * 128 + j]
                        : (h1 < 14 ? shot_w[(h1 - 2) * 128 + j]
                                   : move_w[(h1 - 14) * 128 + j]);
    s_head[j * 8 + p] = packh2(w0, w1);
  }
  if (tid < 32) s_pb[tid] = proj_b[tid];
  if (tid < 128) s_ab[tid] = act_b[tid];
  __syncthreads();

  size_t idx0 = (size_t)blockIdx.x * 512 + tid;
  size_t idx1 = idx0 + 256;
  uint32_t zA[8], zB[8];
  {
    const uint4* za = (const uint4*)(zs + idx0 * 16);
    const uint4* zb = (const uint4*)(zs + idx1 * 16);
    uint4 a0 = za[0], a1 = za[1], b0 = zb[0], b1 = zb[1];
    zA[0] = a0.x; zA[1] = a0.y; zA[2] = a0.z; zA[3] = a0.w;
    zA[4] = a1.x; zA[5] = a1.y; zA[6] = a1.z; zA[7] = a1.w;
    zB[0] = b0.x; zB[1] = b0.y; zB[2] = b0.z; zB[3] = b0.w;
    zB[4] = b1.x; zB[5] = b1.y; zB[6] = b1.z; zB[7] = b1.w;
  }
  uint32_t stA[16], stB[16];
  {
    const uint4* sa = (const uint4*)(state_t + idx0 * 32);
    const uint4* sb = (const uint4*)(state_t + idx1 * 32);
#pragma unroll
    for (int q = 0; q < 4; ++q) {
      uint4 va = sa[q], vb = sb[q];
      stA[4 * q] = va.x; stA[4 * q + 1] = va.y; stA[4 * q + 2] = va.z; stA[4 * q + 3] = va.w;
      stB[4 * q] = vb.x; stB[4 * q + 1] = vb.y; stB[4 * q + 2] = vb.z; stB[4 * q + 3] = vb.w;
    }
  }

  float sqA = 0.0f, sqB = 0.0f;
#pragma unroll 4
  for (int i = 0; i < 32; ++i) {
    const uint4* pw = (const uint4*)&s_proj[i * 8];
    uint4 w0 = pw[0], w1 = pw[1];
    float aA = s_pb[i], aB = s_pb[i];
    DOT4(aA, w0.x, w0.y, w0.z, w0.w, *(const uint4*)&zA[0]);
    DOT4(aA, w1.x, w1.y, w1.z, w1.w, *(const uint4*)&zA[4]);
    DOT4(aB, w0.x, w0.y, w0.z, w0.w, *(const uint4*)&zB[0]);
    DOT4(aB, w1.x, w1.y, w1.z, w1.w, *(const uint4*)&zB[4]);
    f16x2 svA = __builtin_bit_cast(f16x2, stA[i >> 1]);
    f16x2 svB = __builtin_bit_cast(f16x2, stB[i >> 1]);
    float dA = (float)svA[i & 1] - aA;
    float dB = (float)svB[i & 1] - aB;
    sqA += dA * dA;
    sqB += dB * dB;
  }

  float hdA[16], hdB[16];
#pragma unroll
  for (int i = 0; i < 16; ++i) { hdA[i] = 0.0f; hdB[i] = 0.0f; }
#pragma unroll 2
  for (int j = 0; j < 128; ++j) {
    const uint4* aw = (const uint4*)&s_act[j * 8];
    uint4 w0 = aw[0], w1 = aw[1];
    float aA = s_ab[j], aB = s_ab[j];
    DOT4(aA, w0.x, w0.y, w0.z, w0.w, *(const uint4*)&zA[0]);
    DOT4(aA, w1.x, w1.y, w1.z, w1.w, *(const uint4*)&zA[4]);
    DOT4(aB, w0.x, w0.y, w0.z, w0.w, *(const uint4*)&zB[0]);
    DOT4(aB, w1.x, w1.y, w1.z, w1.w, *(const uint4*)&zB[4]);
    aA = fmaxf(aA, 0.0f);
    aB = fmaxf(aB, 0.0f);
    const uint4* hw = (const uint4*)&s_head[j * 8];
    uint4 h0 = hw[0], h1 = hw[1];
    uint32_t whu[8] = {h0.x, h0.y, h0.z, h0.w, h1.x, h1.y, h1.z, h1.w};
#pragma unroll
    for (int p = 0; p < 8; ++p) {
      f16x2 w = __builtin_bit_cast(f16x2, whu[p]);
      float w0f = (float)w[0], w1f = (float)w[1];
      hdA[2 * p] += w0f * aA;
      hdA[2 * p + 1] += w1f * aA;
      hdB[2 * p] += w0f * aB;
      hdB[2 * p + 1] += w1f * aB;
    }
  }

  float vals[5] = {sqA + sqB, 0.f, 0.f, 0.f, 0.f};
#pragma unroll
  for (int tok = 0; tok < 2; ++tok) {
    const float* hd = tok ? hdB : hdA;
    const float* xp = xs + (tok ? idx1 : idx0) * 23;
    float dl0 = hd[0] - xp[18], dl1 = hd[1] - xp[19];
    vals[1] += dl0 * dl0 + dl1 * dl1;
    float dm0 = hd[14] - xp[21], dm1 = hd[15] - xp[22];
    vals[2] += dm0 * dm0 + dm1 * dm1;
    int sid = (int)xp[20];
    float m = hd[2];
#pragma unroll
    for (int s = 1; s < 12; ++s) m = fmaxf(m, hd[2 + s]);
    float sume = 0.0f;
#pragma unroll
    for (int s = 0; s < 12; ++s) sume += __expf(hd[2 + s] - m);
    float lse = m + __logf(sume);
    float pl = 0.0f;
#pragma unroll
    for (int s = 0; s < 12; ++s)
      if (s == sid) pl = hd[2 + s];
    if (sid != 0) {
      vals[3] += pl - lse;
      vals[4] += 1.0f;
    }
  }
#pragma unroll
  for (int v = 0; v < 5; ++v) {
    float x = vals[v];
    for (int off = 1; off < 64; off <<= 1) x += __shfl_xor(x, off);
    vals[v] = x;
  }
  int lane = tid & 63, wv = tid >> 6;
  if (lane == 0) {
#pragma unroll
    for (int v = 0; v < 5; ++v) s_red[wv * 5 + v] = vals[v];
  }
  __syncthreads();
  if (tid == 0) {
#pragma unroll
    for (int v = 0; v < 5; ++v) {
      float s = s_red[v] + s_red[5 + v] + s_red[10 + v] + s_red[15 + v];
      atomicAdd(&accums[v], s);
    }
  }
}

// ---------------------------------------------------------------------------
// Kernel 5: finalize the two scalar outputs.
// ---------------------------------------------------------------------------
__global__ void k_fin(const float* __restrict__ accums,
                      const float* __restrict__ noise_std,
                      float* __restrict__ out) {
  if (threadIdx.x == 0 && blockIdx.x == 0) {
    float sd = noise_std[0];
    float log_pxs = -0.5f * accums[0] / (sd * sd * (float)B_SZ) -
                    (float)T_STEPS * 32.0f * (logf(sd) + 0.5f * LOG2PI);
    float land = accums[1] / (float)(T_STEPS * B_SZ * 2);
    float move = accums[2] / (float)(T_STEPS * B_SZ * 2);
    float shot = -accums[3] / fmaxf(accums[4], 1.0f);
    float out1 = accums[5] / (float)B_SZ + accums[6] / (float)B_SZ + land + shot + move;
    out[0] = log_pxs;
    out[1] = out1;
  }
}

// ---------------------------------------------------------------------------
extern "C" void kernel_launch(void* const* d_in, const int* in_sizes, int n_in,
                              void* d_out, int out_size, void* d_ws,
                              size_t ws_size, hipStream_t stream) {
  const float* xs = (const float*)d_in[1];
  const float* ts = (const float*)d_in[2];
  const float* noise_std = (const float*)d_in[3];
  const float* z0_noise = (const float*)d_in[4];
  const float* bm_noise = (const float*)d_in[5];
  const float* shot_emb = (const float*)d_in[6];
  const float* player_emb = (const float*)d_in[7];
  const float* gru_wih = (const float*)d_in[8];
  const float* gru_whh = (const float*)d_in[9];
  const float* gru_bih = (const float*)d_in[10];
  const float* gru_bhh = (const float*)d_in[11];
  const float* enc_w = (const float*)d_in[12];
  const float* enc_b = (const float*)d_in[13];
  const float* qz0_w = (const float*)d_in[14];
  const float* qz0_b = (const float*)d_in[15];
  const float* f_w1 = (const float*)d_in[16];
  const float* f_b1 = (const float*)d_in[17];
  const float* f_w2 = (const float*)d_in[18];
  const float* f_b2 = (const float*)d_in[19];
  const float* f_w3 = (const float*)d_in[20];
  const float* f_b3 = (const float*)d_in[21];
  const float* h_w1 = (const float*)d_in[22];
  const float* h_b1 = (const float*)d_in[23];
  const float* h_w2 = (const float*)d_in[24];
  const float* h_b2 = (const float*)d_in[25];
  const float* h_w3 = (const float*)d_in[26];
  const float* h_b3 = (const float*)d_in[27];
  const float* g_w1 = (const float*)d_in[28];
  const float* g_b1 = (const float*)d_in[29];
  const float* g_w2 = (const float*)d_in[30];
  const float* g_b2 = (const float*)d_in[31];
  const float* proj_w = (const float*)d_in[32];
  const float* proj_b = (const float*)d_in[33];
  const float* pz0_mean = (const float*)d_in[34];
  const float* pz0_logstd = (const float*)d_in[35];
  const float* act_w = (const float*)d_in[36];
  const float* act_b = (const float*)d_in[37];
  const float* act_land_w = (const float*)d_in[38];
  const float* act_shot_w = (const float*)d_in[39];
  const float* act_move_w = (const float*)d_in[40];

  char* ws = (char*)d_ws;
  float* accums = (float*)ws;                       // 16 floats
  f16* state_t = (f16*)(ws + 256);                  // T*B*32 f16 = 16 MB
  f16* ctx = (f16*)(ws + 256 + 16777216);           // T*B*64 f16 = 32 MB
  float* z0b = (float*)(ws + 256 + 16777216 + 33554432);   // B*16 f32
  f16* zs = (f16*)(ws + 256 + 16777216 + 33554432 + 32768);  // T*B*16 f16 = 8 MB

  k_embed<<<1024, 256, 0, stream>>>(xs, shot_emb, player_emb, state_t, accums);
  k_gru<<<512, 256, 0, stream>>>(state_t, gru_wih, gru_whh, gru_bih, gru_bhh,
                                 enc_w, enc_b, qz0_w, qz0_b, z0_noise, pz0_mean,
                                 pz0_logstd, ctx, z0b, accums);
  k_sde<<<512, 256, 0, stream>>>(ctx, z0b, ts, bm_noise, f_w1, f_b1, f_w2, f_b2,
                                 f_w3, f_b3, h_w1, h_b1, h_w2, h_b2, h_w3, h_b3,
                                 g_w1, g_b1, g_w2, g_b2, zs, accums);
  k_dec<<<512, 256, 0, stream>>>(zs, state_t, xs, proj_w, proj_b, act_w, act_b,
                                 act_land_w, act_shot_w, act_move_w, accums);
  k_fin<<<1, 64, 0, stream>>>(accums, noise_std, (float*)d_out);
}